// Round 8
// baseline (95.828 us; speedup 1.0000x reference)
//
#include <hip/hip_runtime.h>

// labels[b,l,c] = argmin_q ( LN(t)[b,l,c] - LN(code_book)[c,q] )
//              = argmax_q code_book[c,q]   (LN monotone; tn constant along q)
// => output is a 256-entry per-c label vector broadcast over (B, L).
//
// v8: single dispatch, contiguous-sweep scan with deep MLP.
// Lessons encoded:
//  - stride-1024 wave-load segment patterns (v1: 64 segs, v7: 16 segs) are
//    slow (L2 bank/channel camping); v6-K1's contiguous 1 KB row-load is
//    fast -> sweep cb4[k*256 + tid]: 1 KB contiguous per wave-instr, and
//    wave w at step k holds exactly row 4k+w (lane l = cols 4l..4l+3).
//  - v5's 58 us was 64 SERIAL cold misses (1 load per 6-shfl chain);
//    here 8 loads are issued per batch before any reduction (8 outstanding
//    misses/thread), and the 8 butterflies are independent chains.
// Butterfly reduction (value desc, index asc) is bit-exact per v5/v6
// (absmax=0): associative+commutative total order, first-index tie-break.

#define C_DIM 256
#define Q_DIM 256
#define OUT_INT4 (4 * 512 * 256 / 4)   // B*L*C / 4 = 131072 int4 stores
#define NBLOCKS 128

__global__ __launch_bounds__(256) void rpq_fused(const float* __restrict__ cb,
                                                 int* __restrict__ out) {
    __shared__ int s[C_DIM];
    const int tid  = threadIdx.x;
    const int lane = tid & 63;
    const int wave = tid >> 6;
    const float4* cb4 = (const float4*)cb;

#pragma unroll 1
    for (int k = 0; k < 64; k += 8) {
        // Issue 8 independent contiguous loads (1 KB/wave-instr each).
        float4 v[8];
#pragma unroll
        for (int u = 0; u < 8; ++u)
            v[u] = cb4[(k + u) * 256 + tid];
        // 8 independent merge+butterfly chains; wave w, step k+u owns
        // row 4*(k+u)+w with lane l holding cols 4l..4l+3.
#pragma unroll
        for (int u = 0; u < 8; ++u) {
            float b  = v[u].x;
            int  idx = lane * 4;
            if (v[u].y > b) { b = v[u].y; idx = lane * 4 + 1; }
            if (v[u].z > b) { b = v[u].z; idx = lane * 4 + 2; }
            if (v[u].w > b) { b = v[u].w; idx = lane * 4 + 3; }
#pragma unroll
            for (int off = 1; off < 64; off <<= 1) {
                float ob = __shfl_xor(b, off, 64);
                int   oi = __shfl_xor(idx, off, 64);
                if (ob > b || (ob == b && oi < idx)) { b = ob; idx = oi; }
            }
            if (lane == 0) s[4 * (k + u) + wave] = idx;
        }
    }
    __syncthreads();

    // Each thread's int4 payload is invariant across its grid-stride stores:
    // for i = blk*256 + tid + j*32768, (4i) mod 256 == 4*(tid & 63).
    const int base = lane * 4;
    const int4 vv = make_int4(s[base], s[base + 1], s[base + 2], s[base + 3]);
    int4* o4 = (int4*)out;
    for (int i = blockIdx.x * 256 + tid; i < OUT_INT4; i += NBLOCKS * 256) {
        o4[i] = vv;
    }
}

extern "C" void kernel_launch(void* const* d_in, const int* in_sizes, int n_in,
                              void* d_out, int out_size, void* d_ws, size_t ws_size,
                              hipStream_t stream) {
    // inputs: 0=input_values (B,L,D) f32, 1=W (Q,D) f32, 2=code_book (C,Q) f32, 3=raw_signal
    const float* code_book = (const float*)d_in[2];
    int* out = (int*)d_out;
    rpq_fused<<<NBLOCKS, 256, 0, stream>>>(code_book, out);
}

// Round 9
// 70.804 us; speedup vs baseline: 1.3534x; 1.3534x over previous
//
#include <hip/hip_runtime.h>

// labels[b,l,c] = argmin_q ( LN(t)[b,l,c] - LN(code_book)[c,q] )
//              = argmax_q code_book[c,q]   (LN monotone; tn constant along q)
// => output is a 256-entry per-c label vector broadcast over (B, L).
//
// v9: single dispatch, LDS-staged scan. Encodes all three measured rules:
//  (1) contiguous wave-loads only  (v1/v7 stride-1024 gathers: 17-20 us)
//  (2) almost no cross-lane ops    (v5/v8 bulk butterflies: 45-58 us)
//  (3) single dispatch             (second launch costs ~5 us, v6)
// Structure per block (4 chunks of 64 rows):
//  stage:  16 contiguous sweep steps cb4[chunk*4096 + k*256 + tid] ->
//          LDS[rr][c ^ rr] (XOR swizzle; write side: rr fixed per wave,
//          c=lane -> uniform banks; read side: c^rr uniform banks).
//  scan:   thread tid scans quarter p=tid&3 of row rr=tid>>2 from LDS
//          in-lane (ascending col => strict '>' keeps earliest index),
//          then a 2-step shfl_xor merge over the 4-lane group under the
//          total order (value desc, index asc) — associative+commutative,
//          exact first-index tie-break (absmax=0 in v5-v8).
// Only 8 shuffles/thread total; codebook read exactly once per block.

#define C_DIM 256
#define Q_DIM 256
#define OUT_INT4 (4 * 512 * 256 / 4)   // B*L*C / 4 = 131072 int4 stores
#define NBLOCKS 256

__global__ __launch_bounds__(256) void rpq_fused(const float* __restrict__ cb,
                                                 int* __restrict__ out) {
    __shared__ float4 sv[64 * 64];   // one 64-row chunk, XOR-swizzled (64 KB)
    __shared__ int s[C_DIM];
    const int tid  = threadIdx.x;
    const int lane = tid & 63;
    const int wave = tid >> 6;
    const float4* cb4 = (const float4*)cb;

    const int rr_rd = tid >> 2;   // row-within-chunk this thread scans
    const int p     = tid & 3;    // quarter of the row

#pragma unroll 1
    for (int chunk = 0; chunk < 4; ++chunk) {
        // Stage 64 rows: 16 contiguous wave-sweep steps (1 KB/wave-instr).
#pragma unroll
        for (int k = 0; k < 16; ++k) {
            float4 v = cb4[chunk * 4096 + k * 256 + tid];
            const int rr = k * 4 + wave;          // row-within-chunk
            sv[rr * 64 + (lane ^ rr)] = v;        // col4 = lane, swizzled
        }
        __syncthreads();

        // In-lane scan of quarter p (cols 16p..16p+15) of row rr_rd.
        float b  = -3.4e38f;
        int  idx = 0;
#pragma unroll
        for (int j = 0; j < 16; ++j) {
            const int c = p * 16 + j;
            float4 v = sv[rr_rd * 64 + (c ^ rr_rd)];
            const int q = c * 4;
            if (v.x > b) { b = v.x; idx = q; }
            if (v.y > b) { b = v.y; idx = q + 1; }
            if (v.z > b) { b = v.z; idx = q + 2; }
            if (v.w > b) { b = v.w; idx = q + 3; }
        }
        // 2-step merge across the 4-lane group (partners share the row).
#pragma unroll
        for (int off = 1; off < 4; off <<= 1) {
            float ob = __shfl_xor(b, off, 64);
            int   oi = __shfl_xor(idx, off, 64);
            if (ob > b || (ob == b && oi < idx)) { b = ob; idx = oi; }
        }
        if (p == 0) s[chunk * 64 + rr_rd] = idx;
        __syncthreads();   // also protects sv reuse next chunk
    }

    // Each thread's int4 payload is invariant across its grid-stride stores:
    // for i = blk*256 + tid + j*65536, (4i) mod 256 == 4*(tid & 63).
    const int base = lane * 4;
    const int4 vv = make_int4(s[base], s[base + 1], s[base + 2], s[base + 3]);
    int4* o4 = (int4*)out;
    for (int i = blockIdx.x * 256 + tid; i < OUT_INT4; i += NBLOCKS * 256) {
        o4[i] = vv;
    }
}

extern "C" void kernel_launch(void* const* d_in, const int* in_sizes, int n_in,
                              void* d_out, int out_size, void* d_ws, size_t ws_size,
                              hipStream_t stream) {
    // inputs: 0=input_values (B,L,D) f32, 1=W (Q,D) f32, 2=code_book (C,Q) f32, 3=raw_signal
    const float* code_book = (const float*)d_in[2];
    int* out = (int*)d_out;
    rpq_fused<<<NBLOCKS, 256, 0, stream>>>(code_book, out);
}